// Round 1
// 949.654 us; speedup vs baseline: 1.1217x; 1.1217x over previous
//
#include <hip/hip_runtime.h>
#include <math.h>

typedef unsigned int  uint32;
typedef unsigned short u16;
typedef __attribute__((ext_vector_type(8))) short short8;   // 8 bf16 in 4 VGPRs
typedef __attribute__((ext_vector_type(4))) float f32x4;
typedef __attribute__((ext_vector_type(16))) float f32x16;
typedef __attribute__((ext_vector_type(4))) unsigned int u32x4;

#define NB     4
#define CIN    192
#define MID_C  96
#define OC3    288
#define HH     33
#define NWIN   (NB*HH*HH)
#define PADW   264
#define IMGW   256

// ---------- bf16 helpers ----------
__device__ __forceinline__ u16 f2bf(float f) {
    union { float f; uint32 u; } v; v.f = f;
    uint32 u = v.u;
    return (u16)((u + 0x7fffu + ((u >> 16) & 1u)) >> 16);   // RNE
}
__device__ __forceinline__ float bfu_to_f(u16 h) {
    union { uint32 u; float f; } v; v.u = ((uint32)h) << 16; return v.f;
}
__device__ __forceinline__ float hi_trunc_f(uint32 u) {
    union { uint32 u; float f; } v; v.u = (u & 0xffff0000u); return v.f;
}

// ---------- K1: fold BN + shift-mask into packed bf16 weights ----------
struct PrepArgs {
    const float* w[3];
    const float* b[3];
    const float* gamma[3];
    const float* beta[3];
    const float* mean[3];
    const float* var[3];
    const float* w_out;
    const float* b_out;
    u16*   Wbf;    // [288 oc][192 c] bf16 (A-operand layout)
    u16*   WbfO;   // [192 oc][96 c]  bf16
    float* beff;   // [288]
    float* bout;   // [192]
};

__global__ __launch_bounds__(256) void prep_kernel(PrepArgs a) {
    int i = blockIdx.x * 256 + threadIdx.x;
    const int khs[5] = {1,1,2,0,1};
    const int kws[5] = {2,0,1,1,1};
    if (i < 288*192) {
        int oc = i / 192, c = i % 192;
        int t = oc / 96, och = oc % 96;
        int grp = (c < 152) ? (c / 38) : 4;
        float scale = a.gamma[t][och] / sqrtf(a.var[t][och] + 1e-5f);
        float v = a.w[t][(och*192 + c)*9 + khs[grp]*3 + kws[grp]] * scale;
        a.Wbf[i] = f2bf(v);
    } else if (i < 288*192 + 192*96) {
        int j = i - 288*192;
        int o = j / 96, c = j % 96;
        int grp = (c < 76) ? (c / 19) : 4;
        a.WbfO[j] = f2bf(a.w_out[(o*96 + c)*9 + khs[grp]*3 + kws[grp]]);
    } else if (i < 288*192 + 192*96 + 480) {
        int j = i - (288*192 + 192*96);
        if (j < 288) {
            int t = j / 96, och = j % 96;
            float scale = a.gamma[t][och] / sqrtf(a.var[t][och] + 1e-5f);
            a.beff[j] = a.beta[t][och] + (a.b[t][och] - a.mean[t][och]) * scale;
        } else {
            a.bout[j - 288] = a.b_out[j - 288];
        }
    }
}

// ---------- K2: MFMA qkv-conv + MFMA window attention ----------
// one block per (batch, window). 256 threads = 4 waves (wave = 16-px N-tile for
// the conv, then one wave = 2 heads for the attention).
// LDS: xs 2x32x100 bf16 (12800B) + qkv 3x64x100 bf16 (38400B) + shoff (768B) -> 3 blocks/CU
__global__ __launch_bounds__(256, 3) void qkv_attn_kernel(
    const float* __restrict__ x,      // [4][192][256][256]
    const u16*   __restrict__ Wbf,    // [288][192] bf16
    const float* __restrict__ beff,   // [288]
    u16*         __restrict__ attn_sp)// [4][96][264][264] bf16
{
    __shared__ __align__(16) u16 xs[2][32][100];    // hi / lo planes of 32-channel chunk
    __shared__ __align__(16) u16 qkv[3][64][100];
    __shared__ int shoff[192];

    int blk = blockIdx.x;
    int b   = blk / (HH*HH);
    int rem = blk % (HH*HH);
    int wy  = rem / HH;
    int wx  = rem % HH;
    int tid = threadIdx.x;
    int lane = tid & 63;
    int nt   = __builtin_amdgcn_readfirstlane(tid >> 6);   // wave id = N-tile
    int l15  = lane & 15;
    int quad = lane >> 4;

    if (tid < 192) {
        int c = tid;
        int grp = (c < 152) ? (c / 38) : 4;
        int dy = 0, dx = 0;
        if (grp == 0) dx = 1; else if (grp == 1) dx = -1;
        else if (grp == 2) dy = 1; else if (grp == 3) dy = -1;
        shoff[c] = dy*10 + dx;
    }

    int px    = nt*16 + l15;                    // pixel in window (B/D col)
    int pbase = (1 + (px >> 3))*10 + 1 + (px & 7);

    int gy0 = wy*8 - 1;
    int gx0 = wx*8 - 1;

    f32x4 acc[18];
    #pragma unroll
    for (int mt = 0; mt < 18; ++mt) acc[mt] = (f32x4){0.f, 0.f, 0.f, 0.f};

    for (int chunk = 0; chunk < 6; ++chunk) {
        __syncthreads();
        for (int i = tid; i < 3200; i += 256) {
            int cc  = i / 100;
            int pos = i % 100;
            int r   = pos / 10, col = pos % 10;
            int gy  = gy0 + r, gx = gx0 + col;
            float v = 0.f;
            if (gy >= 4 && gy < 260 && gx >= 4 && gx < 260)
                v = x[((b*CIN + chunk*32 + cc)*IMGW + (gy - 4))*IMGW + (gx - 4)];
            u16 h = f2bf(v);
            xs[0][cc][pos] = h;
            xs[1][cc][pos] = f2bf(v - bfu_to_f(h));   // residual -> ~fp32 x
        }
        __syncthreads();

        // B fragments: B[k=c][n=px], k = quad*8 + j
        short8 bh, bl;
        #pragma unroll
        for (int j = 0; j < 8; ++j) {
            int cc  = quad*8 + j;
            int off = pbase + shoff[chunk*32 + cc];
            bh[j] = (short)xs[0][cc][off];
            bl[j] = (short)xs[1][cc][off];
        }
        // A fragments: A[m=oc][k=c], 8 contiguous c -> 16B load (L1-resident)
        const u16* Abase = Wbf + l15*192 + chunk*32 + quad*8;
        #pragma unroll
        for (int mt = 0; mt < 18; ++mt) {
            short8 af = *(const short8*)(Abase + mt*16*192);
            acc[mt] = __builtin_amdgcn_mfma_f32_16x16x32_bf16(af, bh, acc[mt], 0, 0, 0);
            acc[mt] = __builtin_amdgcn_mfma_f32_16x16x32_bf16(af, bl, acc[mt], 0, 0, 0);
        }
    }

    // epilogue: bias, bf16, -> qkv LDS. D: col(l15)=px, row=quad*4+reg = oc%16
    #pragma unroll
    for (int mt = 0; mt < 18; ++mt) {
        #pragma unroll
        for (int r = 0; r < 4; ++r) {
            int oc  = mt*16 + quad*4 + r;
            int t   = oc / 96;
            int och = oc % 96;
            qkv[t][px][och] = f2bf(acc[mt][r] + beff[oc]);
        }
    }
    __syncthreads();

    // ---------------- MFMA attention (swapped-operand flash pattern) ----------------
    // Each wave handles 2 heads. S^T[k][q] = K . Q^T via mfma_32x32x16_bf16
    // (A = K rows, B = Q rows, kdim = 12 channels zero-padded to 16).
    // D layout (guide-verified): col = lane&31 = q, row = (reg&3)+8*(reg>>2)+4*(lane>>5) = k.
    // Softmax per q is therefore 32 in-lane values + one shfl_xor(32).
    // P (pre-scaled by 1/sum) is split into hi/lo bf16 and fed back as the A operand
    // of O = P.V  (A's m-mapping lane&31 == D's col-mapping, so only a half-wave
    // register exchange via shfl_xor(32) is needed).
    {
        const int l31 = lane & 31;
        const int hl  = lane >> 5;                 // half-wave: 0 or 1
        const int vcl = (l31 < 12) ? l31 : 11;     // clamp V channel (cols >=12 unused)

        #pragma unroll 1
        for (int hrep = 0; hrep < 2; ++hrep) {
            const int head  = nt*2 + hrep;
            const int cbase = head*12 + hl*8;      // channel base for A/B kdim

            // load a K/Q fragment: 8 bf16 at row, channels cbase..cbase+7;
            // channels 12..15 (hl==1, j>=4) zeroed on both operands.
            auto ldf = [&](const u16* p) -> short8 {
                const uint32* w = (const uint32*)p;
                union { u32x4 u; short8 s; } t_;
                t_.u[0] = w[0];
                t_.u[1] = w[1];
                t_.u[2] = hl ? 0u : w[2];
                t_.u[3] = hl ? 0u : w[3];
                return t_.s;
            };
            short8 kf0 = ldf(&qkv[1][l31][cbase]);
            short8 kf1 = ldf(&qkv[1][32 + l31][cbase]);
            short8 qf0 = ldf(&qkv[0][l31][cbase]);
            short8 qf1 = ldf(&qkv[0][32 + l31][cbase]);

            f32x16 z;
            #pragma unroll
            for (int i = 0; i < 16; ++i) z[i] = 0.f;

            // sXY: X = k-tile (A: rows 0..31 / 32..63), Y = q-tile (B)
            f32x16 sA0 = __builtin_amdgcn_mfma_f32_32x32x16_bf16(kf0, qf0, z, 0, 0, 0);
            f32x16 sB0 = __builtin_amdgcn_mfma_f32_32x32x16_bf16(kf1, qf0, z, 0, 0, 0);
            f32x16 sA1 = __builtin_amdgcn_mfma_f32_32x32x16_bf16(kf0, qf1, z, 0, 0, 0);
            f32x16 sB1 = __builtin_amdgcn_mfma_f32_32x32x16_bf16(kf1, qf1, z, 0, 0, 0);

            // softmax over one q-column (64 k's = 32 in-lane + partner half)
            auto softmax_col = [&](f32x16& SA, f32x16& SB) {
                float m0 = fmaxf(SA[0], SB[0]);
                float m1 = fmaxf(SA[1], SB[1]);
                float m2 = fmaxf(SA[2], SB[2]);
                float m3 = fmaxf(SA[3], SB[3]);
                #pragma unroll
                for (int i = 4; i < 16; i += 4) {
                    m0 = fmaxf(m0, fmaxf(SA[i+0], SB[i+0]));
                    m1 = fmaxf(m1, fmaxf(SA[i+1], SB[i+1]));
                    m2 = fmaxf(m2, fmaxf(SA[i+2], SB[i+2]));
                    m3 = fmaxf(m3, fmaxf(SA[i+3], SB[i+3]));
                }
                float mx = fmaxf(fmaxf(m0, m1), fmaxf(m2, m3));
                mx = fmaxf(mx, __shfl_xor(mx, 32));
                float s0 = 0.f, s1 = 0.f, s2 = 0.f, s3 = 0.f;
                #pragma unroll
                for (int i = 0; i < 16; i += 4) {
                    SA[i+0] = __expf(SA[i+0] - mx); s0 += SA[i+0];
                    SA[i+1] = __expf(SA[i+1] - mx); s1 += SA[i+1];
                    SA[i+2] = __expf(SA[i+2] - mx); s2 += SA[i+2];
                    SA[i+3] = __expf(SA[i+3] - mx); s3 += SA[i+3];
                    SB[i+0] = __expf(SB[i+0] - mx); s0 += SB[i+0];
                    SB[i+1] = __expf(SB[i+1] - mx); s1 += SB[i+1];
                    SB[i+2] = __expf(SB[i+2] - mx); s2 += SB[i+2];
                    SB[i+3] = __expf(SB[i+3] - mx); s3 += SB[i+3];
                }
                float sum = (s0 + s1) + (s2 + s3);
                sum += __shfl_xor(sum, 32);
                float inv = 1.f / sum;
                #pragma unroll
                for (int i = 0; i < 16; ++i) { SA[i] *= inv; SB[i] *= inv; }
            };
            softmax_col(sA0, sB0);
            softmax_col(sA1, sB1);

            // PV: O[q][c] = sum_k P[q][k] V[k][c].  4 k-steps of 16.
            f32x16 o0 = z, o1 = z;
            #pragma unroll
            for (int ks = 0; ks < 4; ++ks) {
                // V B-fragment: B[k=hl*8+j][n=c], k global = ks*16 + hl*8 + j
                short8 vf;
                #pragma unroll
                for (int j = 0; j < 8; ++j)
                    vf[j] = (short)qkv[2][ks*16 + hl*8 + j][head*12 + vcl];

                // Build P A-fragments (hi+lo bf16) from the two quarters
                // q0=(ks&1)*2, q1=q0+1 of S-tile ks>>1; exchange complementary
                // quarter packs with the partner half-wave (shfl_xor 32).
                auto pv_step = [&](const f32x16& S, f32x16& O) {
                    const int base = (ks & 1) * 8;
                    float p0 = S[base+0], p1 = S[base+1], p2 = S[base+2], p3 = S[base+3];
                    float p4 = S[base+4], p5 = S[base+5], p6 = S[base+6], p7 = S[base+7];
                    uint32 u0 = __float_as_uint(p0), u1 = __float_as_uint(p1);
                    uint32 u2 = __float_as_uint(p2), u3 = __float_as_uint(p3);
                    uint32 u4 = __float_as_uint(p4), u5 = __float_as_uint(p5);
                    uint32 u6 = __float_as_uint(p6), u7 = __float_as_uint(p7);
                    // hi = truncate-to-bf16 (top 16 bits); lo = RNE(p - hi)
                    uint32 h0_01 = (u1 & 0xffff0000u) | (u0 >> 16);
                    uint32 h0_23 = (u3 & 0xffff0000u) | (u2 >> 16);
                    uint32 h1_01 = (u5 & 0xffff0000u) | (u4 >> 16);
                    uint32 h1_23 = (u7 & 0xffff0000u) | (u6 >> 16);
                    uint32 l0_01 = (uint32)f2bf(p0 - hi_trunc_f(u0)) | ((uint32)f2bf(p1 - hi_trunc_f(u1)) << 16);
                    uint32 l0_23 = (uint32)f2bf(p2 - hi_trunc_f(u2)) | ((uint32)f2bf(p3 - hi_trunc_f(u3)) << 16);
                    uint32 l1_01 = (uint32)f2bf(p4 - hi_trunc_f(u4)) | ((uint32)f2bf(p5 - hi_trunc_f(u5)) << 16);
                    uint32 l1_23 = (uint32)f2bf(p6 - hi_trunc_f(u6)) | ((uint32)f2bf(p7 - hi_trunc_f(u7)) << 16);
                    // keep own half's quarter; send the other; receive partner's
                    uint32 kh01 = hl ? h1_01 : h0_01, kh23 = hl ? h1_23 : h0_23;
                    uint32 sh01 = hl ? h0_01 : h1_01, sh23 = hl ? h0_23 : h1_23;
                    uint32 kl01 = hl ? l1_01 : l0_01, kl23 = hl ? l1_23 : l0_23;
                    uint32 sl01 = hl ? l0_01 : l1_01, sl23 = hl ? l0_23 : l1_23;
                    uint32 rh01 = __shfl_xor(sh01, 32);
                    uint32 rh23 = __shfl_xor(sh23, 32);
                    uint32 rl01 = __shfl_xor(sl01, 32);
                    uint32 rl23 = __shfl_xor(sl23, 32);
                    union { u32x4 u; short8 s; } fh, fl;
                    fh.u[0] = hl ? rh01 : kh01;  fh.u[1] = hl ? rh23 : kh23;
                    fh.u[2] = hl ? kh01 : rh01;  fh.u[3] = hl ? kh23 : rh23;
                    fl.u[0] = hl ? rl01 : kl01;  fl.u[1] = hl ? rl23 : kl23;
                    fl.u[2] = hl ? kl01 : rl01;  fl.u[3] = hl ? kl23 : rl23;
                    O = __builtin_amdgcn_mfma_f32_32x32x16_bf16(fh.s, vf, O, 0, 0, 0);
                    O = __builtin_amdgcn_mfma_f32_32x32x16_bf16(fl.s, vf, O, 0, 0, 0);
                };
                if (ks < 2) { pv_step(sA0, o0); pv_step(sA1, o1); }
                else        { pv_step(sB0, o0); pv_step(sB1, o1); }
            }

            // store: D col = lane&31 = c (only c<12 valid), row = q
            if (l31 < 12) {
                u16* ob = attn_sp + (((b*MID_C + head*12 + l31)*PADW + wy*8)*PADW + wx*8);
                #pragma unroll
                for (int r = 0; r < 16; ++r) {
                    const int c0  = (r & 3) + 8*(r >> 2);   // row offset sans hl
                    const int pyw = c0 >> 3;                 // 0..3
                    const int pxw = (c0 & 7) + 4*hl;         // 0..7 (no carry: c0&7 <= 3)
                    ob[pyw*PADW + pxw]       = f2bf(o0[r]);  // q = c0 + 4*hl
                    ob[(pyw+4)*PADW + pxw]   = f2bf(o1[r]);  // q + 32
                }
            }
        }
    }
}

// ---------- K3: MFMA out shift-conv + crop ----------
// one block per 8x8 output tile. 256 threads = 4 waves.
__global__ __launch_bounds__(256) void outconv_kernel(
    const u16*   __restrict__ sp,     // [4][96][264][264] bf16
    const u16*   __restrict__ WbfO,   // [192][96] bf16
    const float* __restrict__ bout,   // [192]
    float*       __restrict__ out)    // [4][192][256][256]
{
    __shared__ u16 xs[96][100];       // 19200B
    __shared__ int shoff[96];

    int blk = blockIdx.x;             // 4*32*32
    int b   = blk >> 10;
    int rem = blk & 1023;
    int ty  = rem >> 5;
    int tx  = rem & 31;
    int tid = threadIdx.x;
    int lane = tid & 63;
    int nt   = __builtin_amdgcn_readfirstlane(tid >> 6);
    int l15  = lane & 15;
    int quad = lane >> 4;

    if (tid < 96) {
        int c = tid;
        int grp = (c < 76) ? (c / 19) : 4;
        int dy = 0, dx = 0;
        if (grp == 0) dx = 1; else if (grp == 1) dx = -1;
        else if (grp == 2) dy = 1; else if (grp == 3) dy = -1;
        shoff[c] = dy*10 + dx;
    }

    int py0 = ty*8 + 3;
    int px0 = tx*8 + 3;
    for (int i = tid; i < 9600; i += 256) {
        int c   = i / 100;
        int pos = i % 100;
        int r   = pos / 10, col = pos % 10;
        xs[c][pos] = sp[((b*MID_C + c)*PADW + (py0 + r))*PADW + (px0 + col)];
    }
    __syncthreads();

    int px    = nt*16 + l15;
    int pbase = (1 + (px >> 3))*10 + 1 + (px & 7);

    f32x4 acc[12];
    #pragma unroll
    for (int mt = 0; mt < 12; ++mt) acc[mt] = (f32x4){0.f, 0.f, 0.f, 0.f};

    #pragma unroll
    for (int ks = 0; ks < 3; ++ks) {
        short8 bf;
        #pragma unroll
        for (int j = 0; j < 8; ++j) {
            int cc = ks*32 + quad*8 + j;
            bf[j] = (short)xs[cc][pbase + shoff[cc]];
        }
        const u16* Abase = WbfO + l15*96 + ks*32 + quad*8;
        #pragma unroll
        for (int mt = 0; mt < 12; ++mt) {
            short8 af = *(const short8*)(Abase + mt*16*96);
            acc[mt] = __builtin_amdgcn_mfma_f32_16x16x32_bf16(af, bf, acc[mt], 0, 0, 0);
        }
    }

    int qy = px >> 3, qx = px & 7;
    int oy = ty*8 + qy, ox = tx*8 + qx;
    #pragma unroll
    for (int mt = 0; mt < 12; ++mt) {
        #pragma unroll
        for (int r = 0; r < 4; ++r) {
            int oc = mt*16 + quad*4 + r;
            out[((b*CIN + oc)*IMGW + oy)*IMGW + ox] = acc[mt][r] + bout[oc];
        }
    }
}

// ---------- launcher ----------
extern "C" void kernel_launch(void* const* d_in, const int* in_sizes, int n_in,
                              void* d_out, int out_size, void* d_ws, size_t ws_size,
                              hipStream_t stream) {
    const float* x = (const float*)d_in[0];

    PrepArgs a;
    for (int t = 0; t < 3; ++t) {
        a.w[t]     = (const float*)d_in[1 + 6*t];
        a.b[t]     = (const float*)d_in[2 + 6*t];
        a.gamma[t] = (const float*)d_in[3 + 6*t];
        a.beta[t]  = (const float*)d_in[4 + 6*t];
        a.mean[t]  = (const float*)d_in[5 + 6*t];
        a.var[t]   = (const float*)d_in[6 + 6*t];
    }
    a.w_out = (const float*)d_in[19];
    a.b_out = (const float*)d_in[20];

    char* ws = (char*)d_ws;
    u16*   Wbf     = (u16*)ws;                         // 110592 B
    u16*   WbfO    = (u16*)(ws + 110592);              //  36864 B
    float* beff    = (float*)(ws + 147456);            //   1152 B
    float* bout    = (float*)(ws + 148608);            //    768 B
    u16*   attn_sp = (u16*)(ws + 149504);              // 4*96*264*264*2 = 53526528 B

    a.Wbf = Wbf; a.WbfO = WbfO; a.beff = beff; a.bout = bout;

    const int prep_items = 288*192 + 192*96 + 480;
    prep_kernel<<<(prep_items + 255)/256, 256, 0, stream>>>(a);
    qkv_attn_kernel<<<NWIN, 256, 0, stream>>>(x, Wbf, beff, attn_sp);
    outconv_kernel<<<NB*32*32, 256, 0, stream>>>(attn_sp, WbfO, bout, (float*)d_out);
}

// Round 3
// 726.148 us; speedup vs baseline: 1.4669x; 1.3078x over previous
//
#include <hip/hip_runtime.h>
#include <math.h>

typedef unsigned int  uint32;
typedef unsigned short u16;
typedef __attribute__((ext_vector_type(8))) short short8;   // 8 bf16 in 4 VGPRs
typedef __attribute__((ext_vector_type(4))) float f32x4;
typedef __attribute__((ext_vector_type(16))) float f32x16;
typedef __attribute__((ext_vector_type(4))) unsigned int u32x4;

#define NB     4
#define CIN    192
#define MID_C  96
#define OC3    288
#define HH     33
#define NWIN   (NB*HH*HH)
#define PADW   264
#define IMGW   256

// ---------- bf16 helpers ----------
__device__ __forceinline__ u16 f2bf(float f) {
    union { float f; uint32 u; } v; v.f = f;
    uint32 u = v.u;
    return (u16)((u + 0x7fffu + ((u >> 16) & 1u)) >> 16);   // RNE
}
__device__ __forceinline__ float bfu_to_f(u16 h) {
    union { uint32 u; float f; } v; v.u = ((uint32)h) << 16; return v.f;
}
__device__ __forceinline__ float bf_lo(uint32 u) {
    union { uint32 u; float f; } v; v.u = (u << 16); return v.f;
}
__device__ __forceinline__ float bf_hi(uint32 u) {
    union { uint32 u; float f; } v; v.u = (u & 0xffff0000u); return v.f;
}
__device__ __forceinline__ float hi_trunc_f(uint32 u) {
    union { uint32 u; float f; } v; v.u = (u & 0xffff0000u); return v.f;
}
// packed f32x2 -> bf16x2 (RNE), low16 = first operand
__device__ __forceinline__ uint32 cvtpk_bf16(float a, float b) {
    uint32 r;
    asm("v_cvt_pk_bf16_f32 %0, %1, %2" : "=v"(r) : "v"(a), "v"(b));
    return r;
}

// ---------- K1: fold BN + shift-mask into packed bf16 weights ----------
struct PrepArgs {
    const float* w[3];
    const float* b[3];
    const float* gamma[3];
    const float* beta[3];
    const float* mean[3];
    const float* var[3];
    const float* w_out;
    const float* b_out;
    u16*   Wbf;    // [288 oc][192 c] bf16 (A-operand layout)
    u16*   WbfO;   // [192 oc][96 c]  bf16
    float* beff;   // [288]
    float* bout;   // [192]
};

__global__ __launch_bounds__(256) void prep_kernel(PrepArgs a) {
    int i = blockIdx.x * 256 + threadIdx.x;
    const int khs[5] = {1,1,2,0,1};
    const int kws[5] = {2,0,1,1,1};
    if (i < 288*192) {
        int oc = i / 192, c = i % 192;
        int t = oc / 96, och = oc % 96;
        int grp = (c < 152) ? (c / 38) : 4;
        float scale = a.gamma[t][och] / sqrtf(a.var[t][och] + 1e-5f);
        float v = a.w[t][(och*192 + c)*9 + khs[grp]*3 + kws[grp]] * scale;
        a.Wbf[i] = f2bf(v);
    } else if (i < 288*192 + 192*96) {
        int j = i - 288*192;
        int o = j / 96, c = j % 96;
        int grp = (c < 76) ? (c / 19) : 4;
        a.WbfO[j] = f2bf(a.w_out[(o*96 + c)*9 + khs[grp]*3 + kws[grp]]);
    } else if (i < 288*192 + 192*96 + 480) {
        int j = i - (288*192 + 192*96);
        if (j < 288) {
            int t = j / 96, och = j % 96;
            float scale = a.gamma[t][och] / sqrtf(a.var[t][och] + 1e-5f);
            a.beff[j] = a.beta[t][och] + (a.b[t][och] - a.mean[t][och]) * scale;
        } else {
            a.bout[j - 288] = a.b_out[j - 288];
        }
    }
}

// ---------- K2: MFMA qkv-conv + MFMA window attention ----------
// one block per (batch, window). 256 threads = 4 waves.
// Staging: T14 async split — per-thread precomputed offsets, reg-double-buffered
// prefetch of chunk c+1 issued before converting/computing chunk c.
// xs LDS holds (hi,lo) bf16 interleaved per element as one u32.
// LDS: xs 12800B + qkv 38400B + shoff 768B = 51968B -> 3 blocks/CU
__global__ __launch_bounds__(256, 3) void qkv_attn_kernel(
    const float* __restrict__ x,      // [4][192][256][256]
    const u16*   __restrict__ Wbf,    // [288][192] bf16
    const float* __restrict__ beff,   // [288]
    u16*         __restrict__ attn_sp)// [4][96][264][264] bf16
{
    __shared__ uint32 xs32[3200];                   // [32 ch][100 pos] (hi|lo<<16)
    __shared__ __align__(16) u16 qkv[3][64][100];
    __shared__ int shoff[192];

    int blk = blockIdx.x;
    int b   = blk / (HH*HH);
    int rem = blk % (HH*HH);
    int wy  = rem / HH;
    int wx  = rem % HH;
    int tid = threadIdx.x;
    int lane = tid & 63;
    int nt   = __builtin_amdgcn_readfirstlane(tid >> 6);   // wave id
    int l15  = lane & 15;
    int quad = lane >> 4;

    if (tid < 192) {
        int c = tid;
        int grp = (c < 152) ? (c / 38) : 4;
        int dy = 0, dx = 0;
        if (grp == 0) dx = 1; else if (grp == 1) dx = -1;
        else if (grp == 2) dy = 1; else if (grp == 3) dy = -1;
        shoff[c] = dy*10 + dx;
    }

    int px    = nt*16 + l15;                    // pixel in window (B/D col)
    int pbase = (1 + (px >> 3))*10 + 1 + (px & 7);

    int gy0 = wy*8 - 1;
    int gx0 = wx*8 - 1;
    const bool border = (wy == 0) || (wy == 32) || (wx == 0) || (wx == 32);

    // ---- one-time per-thread staging precompute (hoists div/mod + bounds) ----
    int   goff[13];
    float emul[13];
    #pragma unroll
    for (int k = 0; k < 13; ++k) {
        int p   = tid + (k << 8);          // element index; k=12 only valid tid<128
        int pp  = (p < 3200) ? p : 0;
        int cc  = pp / 100;
        int pos = pp % 100;
        int r   = pos / 10, col = pos % 10;
        int gy  = gy0 + r, gx = gx0 + col;
        bool valid = (gy >= 4) && (gy < 260) && (gx >= 4) && (gx < 260);
        int cgy = min(max(gy, 4), 259);
        int cgx = min(max(gx, 4), 259);
        goff[k] = cc*65536 + (cgy - 4)*256 + (cgx - 4);
        emul[k] = valid ? 1.f : 0.f;
    }

    const float* xb = x + (size_t)(b*CIN)*65536;

    f32x4 acc[18];
    #pragma unroll
    for (int mt = 0; mt < 18; ++mt) acc[mt] = (f32x4){0.f, 0.f, 0.f, 0.f};

    float bufA[13], bufB[13];

    auto LOADX = [&](float* buf, int chunk) {
        const float* bp = xb + chunk*(32*65536);
        #pragma unroll
        for (int k = 0; k < 12; ++k) buf[k] = bp[goff[k]];
        if (tid < 128) buf[12] = bp[goff[12]];
    };

    auto STOREX = [&](float* buf) {
        if (border) {
            #pragma unroll
            for (int k = 0; k < 12; ++k) buf[k] *= emul[k];
            if (tid < 128) buf[12] *= emul[12];
        }
        #pragma unroll
        for (int kk = 0; kk < 6; ++kk) {
            float v0 = buf[2*kk], v1 = buf[2*kk+1];
            uint32 ph = cvtpk_bf16(v0, v1);
            uint32 pl = cvtpk_bf16(v0 - bf_lo(ph), v1 - bf_hi(ph));
            xs32[tid + (2*kk)*256]   = (ph & 0xffffu) | (pl << 16);
            xs32[tid + (2*kk+1)*256] = (ph >> 16)     | (pl & 0xffff0000u);
        }
        if (tid < 128) {
            float v = buf[12];
            uint32 ph = cvtpk_bf16(v, v);
            uint32 pl = cvtpk_bf16(v - bf_lo(ph), 0.f);
            xs32[tid + 12*256] = (ph & 0xffffu) | (pl << 16);
        }
    };

    auto COMPUTE = [&](int chunk) {
        short8 bh, bl;
        #pragma unroll
        for (int j = 0; j < 8; ++j) {
            int cc = quad*8 + j;
            uint32 w = xs32[cc*100 + pbase + shoff[chunk*32 + cc]];
            bh[j] = (short)(u16)(w & 0xffffu);
            bl[j] = (short)(u16)(w >> 16);
        }
        const u16* Abase = Wbf + l15*192 + chunk*32 + quad*8;
        #pragma unroll
        for (int mt = 0; mt < 18; ++mt) {
            short8 af = *(const short8*)(Abase + mt*16*192);
            acc[mt] = __builtin_amdgcn_mfma_f32_16x16x32_bf16(af, bh, acc[mt], 0, 0, 0);
            acc[mt] = __builtin_amdgcn_mfma_f32_16x16x32_bf16(af, bl, acc[mt], 0, 0, 0);
        }
    };

    LOADX(bufA, 0);
    #pragma unroll
    for (int cpair = 0; cpair < 3; ++cpair) {
        const int c0 = cpair*2;
        LOADX(bufB, c0 + 1);          // issue next-chunk loads (stay in flight)
        __syncthreads();              // prev compute done reading xs
        STOREX(bufA);                 // waits only bufA's loads
        __syncthreads();
        COMPUTE(c0);
        if (cpair < 2) LOADX(bufA, c0 + 2);
        __syncthreads();
        STOREX(bufB);
        __syncthreads();
        COMPUTE(c0 + 1);
    }

    // epilogue: bias, bf16, -> qkv LDS. D: col(l15)=px, row=quad*4+reg = oc%16
    #pragma unroll
    for (int mt = 0; mt < 18; ++mt) {
        #pragma unroll
        for (int r = 0; r < 4; ++r) {
            int oc  = mt*16 + quad*4 + r;
            int t   = oc / 96;
            int och = oc % 96;
            qkv[t][px][och] = f2bf(acc[mt][r] + beff[oc]);
        }
    }
    __syncthreads();

    // ---------------- MFMA attention (swapped-operand flash pattern) ----------------
    {
        const int l31 = lane & 31;
        const int hl  = lane >> 5;                 // half-wave: 0 or 1
        const int vcl = (l31 < 12) ? l31 : 11;     // clamp V channel (cols >=12 unused)

        #pragma unroll 1
        for (int hrep = 0; hrep < 2; ++hrep) {
            const int head  = nt*2 + hrep;
            const int cbase = head*12 + hl*8;      // channel base for A/B kdim

            auto ldf = [&](const u16* p) -> short8 {
                const uint32* w = (const uint32*)p;
                union { u32x4 u; short8 s; } t_;
                t_.u[0] = w[0];
                t_.u[1] = w[1];
                t_.u[2] = hl ? 0u : w[2];
                t_.u[3] = hl ? 0u : w[3];
                return t_.s;
            };
            short8 kf0 = ldf(&qkv[1][l31][cbase]);
            short8 kf1 = ldf(&qkv[1][32 + l31][cbase]);
            short8 qf0 = ldf(&qkv[0][l31][cbase]);
            short8 qf1 = ldf(&qkv[0][32 + l31][cbase]);

            f32x16 z;
            #pragma unroll
            for (int i = 0; i < 16; ++i) z[i] = 0.f;

            f32x16 sA0 = __builtin_amdgcn_mfma_f32_32x32x16_bf16(kf0, qf0, z, 0, 0, 0);
            f32x16 sB0 = __builtin_amdgcn_mfma_f32_32x32x16_bf16(kf1, qf0, z, 0, 0, 0);
            f32x16 sA1 = __builtin_amdgcn_mfma_f32_32x32x16_bf16(kf0, qf1, z, 0, 0, 0);
            f32x16 sB1 = __builtin_amdgcn_mfma_f32_32x32x16_bf16(kf1, qf1, z, 0, 0, 0);

            auto softmax_col = [&](f32x16& SA, f32x16& SB) {
                float m0 = fmaxf(SA[0], SB[0]);
                float m1 = fmaxf(SA[1], SB[1]);
                float m2 = fmaxf(SA[2], SB[2]);
                float m3 = fmaxf(SA[3], SB[3]);
                #pragma unroll
                for (int i = 4; i < 16; i += 4) {
                    m0 = fmaxf(m0, fmaxf(SA[i+0], SB[i+0]));
                    m1 = fmaxf(m1, fmaxf(SA[i+1], SB[i+1]));
                    m2 = fmaxf(m2, fmaxf(SA[i+2], SB[i+2]));
                    m3 = fmaxf(m3, fmaxf(SA[i+3], SB[i+3]));
                }
                float mx = fmaxf(fmaxf(m0, m1), fmaxf(m2, m3));
                mx = fmaxf(mx, __shfl_xor(mx, 32));
                float s0 = 0.f, s1 = 0.f, s2 = 0.f, s3 = 0.f;
                #pragma unroll
                for (int i = 0; i < 16; i += 4) {
                    SA[i+0] = __expf(SA[i+0] - mx); s0 += SA[i+0];
                    SA[i+1] = __expf(SA[i+1] - mx); s1 += SA[i+1];
                    SA[i+2] = __expf(SA[i+2] - mx); s2 += SA[i+2];
                    SA[i+3] = __expf(SA[i+3] - mx); s3 += SA[i+3];
                    SB[i+0] = __expf(SB[i+0] - mx); s0 += SB[i+0];
                    SB[i+1] = __expf(SB[i+1] - mx); s1 += SB[i+1];
                    SB[i+2] = __expf(SB[i+2] - mx); s2 += SB[i+2];
                    SB[i+3] = __expf(SB[i+3] - mx); s3 += SB[i+3];
                }
                float sum = (s0 + s1) + (s2 + s3);
                sum += __shfl_xor(sum, 32);
                float inv = 1.f / sum;
                #pragma unroll
                for (int i = 0; i < 16; ++i) { SA[i] *= inv; SB[i] *= inv; }
            };
            softmax_col(sA0, sB0);
            softmax_col(sA1, sB1);

            f32x16 o0 = z, o1 = z;
            #pragma unroll
            for (int ks = 0; ks < 4; ++ks) {
                short8 vf;
                #pragma unroll
                for (int j = 0; j < 8; ++j)
                    vf[j] = (short)qkv[2][ks*16 + hl*8 + j][head*12 + vcl];

                auto pv_step = [&](const f32x16& S, f32x16& O) {
                    const int base = (ks & 1) * 8;
                    float p0 = S[base+0], p1 = S[base+1], p2 = S[base+2], p3 = S[base+3];
                    float p4 = S[base+4], p5 = S[base+5], p6 = S[base+6], p7 = S[base+7];
                    uint32 u0 = __float_as_uint(p0), u1 = __float_as_uint(p1);
                    uint32 u2 = __float_as_uint(p2), u3 = __float_as_uint(p3);
                    uint32 u4 = __float_as_uint(p4), u5 = __float_as_uint(p5);
                    uint32 u6 = __float_as_uint(p6), u7 = __float_as_uint(p7);
                    uint32 h0_01 = (u1 & 0xffff0000u) | (u0 >> 16);
                    uint32 h0_23 = (u3 & 0xffff0000u) | (u2 >> 16);
                    uint32 h1_01 = (u5 & 0xffff0000u) | (u4 >> 16);
                    uint32 h1_23 = (u7 & 0xffff0000u) | (u6 >> 16);
                    uint32 l0_01 = (uint32)f2bf(p0 - hi_trunc_f(u0)) | ((uint32)f2bf(p1 - hi_trunc_f(u1)) << 16);
                    uint32 l0_23 = (uint32)f2bf(p2 - hi_trunc_f(u2)) | ((uint32)f2bf(p3 - hi_trunc_f(u3)) << 16);
                    uint32 l1_01 = (uint32)f2bf(p4 - hi_trunc_f(u4)) | ((uint32)f2bf(p5 - hi_trunc_f(u5)) << 16);
                    uint32 l1_23 = (uint32)f2bf(p6 - hi_trunc_f(u6)) | ((uint32)f2bf(p7 - hi_trunc_f(u7)) << 16);
                    uint32 kh01 = hl ? h1_01 : h0_01, kh23 = hl ? h1_23 : h0_23;
                    uint32 sh01 = hl ? h0_01 : h1_01, sh23 = hl ? h0_23 : h1_23;
                    uint32 kl01 = hl ? l1_01 : l0_01, kl23 = hl ? l1_23 : l0_23;
                    uint32 sl01 = hl ? l0_01 : l1_01, sl23 = hl ? l0_23 : l1_23;
                    uint32 rh01 = __shfl_xor(sh01, 32);
                    uint32 rh23 = __shfl_xor(sh23, 32);
                    uint32 rl01 = __shfl_xor(sl01, 32);
                    uint32 rl23 = __shfl_xor(sl23, 32);
                    union { u32x4 u; short8 s; } fh, fl;
                    fh.u[0] = hl ? rh01 : kh01;  fh.u[1] = hl ? rh23 : kh23;
                    fh.u[2] = hl ? kh01 : rh01;  fh.u[3] = hl ? kh23 : rh23;
                    fl.u[0] = hl ? rl01 : kl01;  fl.u[1] = hl ? rl23 : kl23;
                    fl.u[2] = hl ? kl01 : rl01;  fl.u[3] = hl ? kl23 : rl23;
                    O = __builtin_amdgcn_mfma_f32_32x32x16_bf16(fh.s, vf, O, 0, 0, 0);
                    O = __builtin_amdgcn_mfma_f32_32x32x16_bf16(fl.s, vf, O, 0, 0, 0);
                };
                if (ks < 2) { pv_step(sA0, o0); pv_step(sA1, o1); }
                else        { pv_step(sB0, o0); pv_step(sB1, o1); }
            }

            // store: D col = lane&31 = c (only c<12 valid), row = q
            // pairs (r, r+1), even r, are x-adjacent and u32-aligned -> packed b32 stores
            if (l31 < 12) {
                u16* ob = attn_sp + (((b*MID_C + head*12 + l31)*PADW + wy*8)*PADW + wx*8);
                #pragma unroll
                for (int r = 0; r < 16; r += 2) {
                    const int c0  = (r & 3) + 8*(r >> 2);   // even
                    const int pyw = c0 >> 3;
                    const int pxw = (c0 & 7) + 4*hl;        // even
                    *(uint32*)&ob[pyw*PADW + pxw]     = cvtpk_bf16(o0[r], o0[r+1]);
                    *(uint32*)&ob[(pyw+4)*PADW + pxw] = cvtpk_bf16(o1[r], o1[r+1]);
                }
            }
        }
    }
}

// ---------- K3: MFMA out shift-conv + crop ----------
// one block per 8x16 output tile (2048 blocks). 256 threads = 4 waves; each wave
// owns a 48-oc slice x all 8 row-tiles. u32-coalesced staging; full-64B-line stores.
__global__ __launch_bounds__(256, 3) void outconv_kernel(
    const u16*   __restrict__ sp,     // [4][96][264][264] bf16
    const u16*   __restrict__ WbfO,   // [192][96] bf16
    const float* __restrict__ bout,   // [192]
    float*       __restrict__ out)    // [4][192][256][256]
{
    __shared__ u16 xs[96][10][20];    // 38400B, patch cols px0-1 .. px0+18
    __shared__ int shoff[96];

    int blk = blockIdx.x;             // 4*32*16
    int b   = blk >> 9;
    int rem = blk & 511;
    int ty  = rem >> 4;
    int tx  = rem & 15;
    int tid = threadIdx.x;
    int lane = tid & 63;
    int ntw  = __builtin_amdgcn_readfirstlane(tid >> 6);
    int l15  = lane & 15;
    int quad = lane >> 4;

    if (tid < 96) {
        int c = tid;
        int grp = (c < 76) ? (c / 19) : 4;
        int dy = 0, dx = 0;
        if (grp == 0) dx = 1; else if (grp == 1) dx = -1;
        else if (grp == 2) dy = 1; else if (grp == 3) dy = -1;
        shoff[c] = dy*20 + dx;
    }

    int py0  = ty*8 + 3;
    int px0m = tx*16 + 2;             // even -> u32-aligned rows

    // staging: 96 ch x 10 rows x 10 u32 (20 bf16). thread -> (chan group, u)
    {
        const uint32* spu = (const uint32*)sp;
        uint32* xw = (uint32*)&xs[0][0][0];
        int c0 = (tid >> 5) * 12;
        int u  = tid & 31;
        #pragma unroll
        for (int j = 0; j < 4; ++j) {
            int uu = u + 32*j;
            if (uu < 100) {
                int r = uu / 10, w = uu % 10;
                int rb = (((py0 + r)*PADW + px0m) >> 1) + w;
                #pragma unroll
                for (int m = 0; m < 12; ++m) {
                    int c = c0 + m;
                    xw[c*100 + r*10 + w] = spu[(b*MID_C + c)*34848 + rb];
                }
            }
        }
    }
    __syncthreads();

    const u16* xf = &xs[0][0][0];

    f32x4 acc[3][8];
    #pragma unroll
    for (int mt = 0; mt < 3; ++mt)
        #pragma unroll
        for (int np = 0; np < 8; ++np) acc[mt][np] = (f32x4){0.f, 0.f, 0.f, 0.f};

    #pragma unroll
    for (int ks = 0; ks < 3; ++ks) {
        short8 bfr[8];
        #pragma unroll
        for (int np = 0; np < 8; ++np) {
            int pb = (1 + np)*20 + 2 + l15;
            #pragma unroll
            for (int j = 0; j < 8; ++j) {
                int cc = ks*32 + quad*8 + j;
                bfr[np][j] = (short)xf[cc*200 + pb + shoff[cc]];
            }
        }
        const u16* Ab = WbfO + (ntw*48)*96 + l15*96 + ks*32 + quad*8;
        #pragma unroll
        for (int mt = 0; mt < 3; ++mt) {
            short8 af = *(const short8*)(Ab + mt*16*96);
            #pragma unroll
            for (int np = 0; np < 8; ++np)
                acc[mt][np] = __builtin_amdgcn_mfma_f32_16x16x32_bf16(af, bfr[np], acc[mt][np], 0, 0, 0);
        }
    }

    int oxb = tx*16 + l15;
    #pragma unroll
    for (int mt = 0; mt < 3; ++mt) {
        #pragma unroll
        for (int rr = 0; rr < 4; ++rr) {
            int oc = ntw*48 + mt*16 + quad*4 + rr;
            float bo = bout[oc];
            #pragma unroll
            for (int np = 0; np < 8; ++np) {
                int oy = ty*8 + np;
                out[((b*CIN + oc)*IMGW + oy)*IMGW + oxb] = acc[mt][np][rr] + bo;
            }
        }
    }
}

// ---------- launcher ----------
extern "C" void kernel_launch(void* const* d_in, const int* in_sizes, int n_in,
                              void* d_out, int out_size, void* d_ws, size_t ws_size,
                              hipStream_t stream) {
    const float* x = (const float*)d_in[0];

    PrepArgs a;
    for (int t = 0; t < 3; ++t) {
        a.w[t]     = (const float*)d_in[1 + 6*t];
        a.b[t]     = (const float*)d_in[2 + 6*t];
        a.gamma[t] = (const float*)d_in[3 + 6*t];
        a.beta[t]  = (const float*)d_in[4 + 6*t];
        a.mean[t]  = (const float*)d_in[5 + 6*t];
        a.var[t]   = (const float*)d_in[6 + 6*t];
    }
    a.w_out = (const float*)d_in[19];
    a.b_out = (const float*)d_in[20];

    char* ws = (char*)d_ws;
    u16*   Wbf     = (u16*)ws;                         // 110592 B
    u16*   WbfO    = (u16*)(ws + 110592);              //  36864 B
    float* beff    = (float*)(ws + 147456);            //   1152 B
    float* bout    = (float*)(ws + 148608);            //    768 B
    u16*   attn_sp = (u16*)(ws + 149504);              // 4*96*264*264*2 = 53526528 B

    a.Wbf = Wbf; a.WbfO = WbfO; a.beff = beff; a.bout = bout;

    const int prep_items = 288*192 + 192*96 + 480;
    prep_kernel<<<(prep_items + 255)/256, 256, 0, stream>>>(a);
    qkv_attn_kernel<<<NWIN, 256, 0, stream>>>(x, Wbf, beff, attn_sp);
    outconv_kernel<<<NB*32*16, 256, 0, stream>>>(attn_sp, WbfO, bout, (float*)d_out);
}